// Round 2
// baseline (1948.199 us; speedup 1.0000x reference)
//
#include <hip/hip_runtime.h>
#include <hip/hip_bf16.h>

#define H 768
#define SEQ 256
#define NPAIR 32896        // S*(S+1)/2
#define NOUT 146           // 2 + 72 + 72
#define NOUTP 160          // padded rows (zeros)
#define TILE_P 16

#define OFF_H2H 263168u            // 4*32896*2
#define OFF_T2T 9737216u           // OFF_H2H + 4*24*32896*3

__device__ __forceinline__ float fast_tanh(float x) {
    // 1 - 2/(e^{2x}+1): monotone-safe at +/-inf (no NaN), ~1e-6 abs err
    return 1.0f - __fdividef(2.0f, __expf(2.0f * x) + 1.0f);
}

// row_start(i) = i*S - i*(i-1)/2
__device__ __forceinline__ int row_start(int i) { return i * SEQ - (i * (i - 1)) / 2; }

__device__ __forceinline__ void pair_ij(int p, int& oi, int& oj) {
    double disc = 263169.0 - 8.0 * (double)p;   // (2S+1)^2 - 8p
    int i = (int)((513.0 - sqrt(disc)) * 0.5);
    if (i > 0 && row_start(i) > p) --i;
    while (row_start(i + 1) <= p) ++i;
    oi = i;
    oj = i + (p - row_start(i));
}

// ---------- kernel 0: pack weights 146x768 (+pad to 160) + biases ----------
__global__ __launch_bounds__(256) void pack_w_kernel(
    const float* __restrict__ h2t_w, const float* __restrict__ h2h_w,
    const float* __restrict__ t2t_w, const float* __restrict__ h2t_b,
    const float* __restrict__ h2h_b, const float* __restrict__ t2t_b,
    float* __restrict__ Wc, float* __restrict__ bc)
{
    int idx = blockIdx.x * 256 + threadIdx.x;
    if (idx < NOUTP * H) {
        int r = idx / H, c = idx % H;
        float v = 0.0f;
        if (r < 2)        v = h2t_w[r * H + c];
        else if (r < 74)  v = h2h_w[(r - 2) * H + c];
        else if (r < 146) v = t2t_w[(r - 74) * H + c];
        Wc[idx] = v;
    }
    if (idx < NOUTP) {
        float v = 0.0f;
        if (idx < 2)        v = h2t_b[idx];
        else if (idx < 74)  v = h2h_b[idx - 2];
        else if (idx < 146) v = t2t_b[idx - 74];
        bc[idx] = v;
    }
}

// ---------- kernel 1: LB[m][o] = sum_h hidden[m][h]*fc_w[o][h] + fc_b[o]
//                      RB[m][o] = sum_h hidden[m][h]*fc_w[o][768+h] ----------
__global__ __launch_bounds__(256) void lr_kernel(
    const float* __restrict__ hidden, const float* __restrict__ fc_w,
    const float* __restrict__ fc_b, float* __restrict__ LB, float* __restrict__ RB)
{
    __shared__ float As[32][65];   // [k][m]
    __shared__ float Ls[32][65];   // [k][o]
    __shared__ float Rs[32][65];
    const int m0 = blockIdx.x * 64, o0 = blockIdx.y * 64;
    const int tid = threadIdx.x, tx = tid & 15, ty = tid >> 4;
    float accL[4][4] = {{0}}, accR[4][4] = {{0}};
    for (int k0 = 0; k0 < H; k0 += 32) {
        for (int t = tid; t < 64 * 32; t += 256) {
            int m = t >> 5, k = t & 31;
            As[k][m] = hidden[(size_t)(m0 + m) * H + k0 + k];
        }
        for (int t = tid; t < 64 * 32; t += 256) {
            int o = t >> 5, k = t & 31;
            const float* wr = fc_w + (size_t)(o0 + o) * (2 * H) + k0 + k;
            Ls[k][o] = wr[0];
            Rs[k][o] = wr[H];
        }
        __syncthreads();
        #pragma unroll
        for (int k = 0; k < 32; ++k) {
            float a[4], l[4], r[4];
            #pragma unroll
            for (int i = 0; i < 4; ++i) a[i] = As[k][tx * 4 + i];
            #pragma unroll
            for (int j = 0; j < 4; ++j) { l[j] = Ls[k][ty * 4 + j]; r[j] = Rs[k][ty * 4 + j]; }
            #pragma unroll
            for (int i = 0; i < 4; ++i)
                #pragma unroll
                for (int j = 0; j < 4; ++j) {
                    accL[i][j] = fmaf(a[i], l[j], accL[i][j]);
                    accR[i][j] = fmaf(a[i], r[j], accR[i][j]);
                }
        }
        __syncthreads();
    }
    #pragma unroll
    for (int i = 0; i < 4; ++i)
        #pragma unroll
        for (int j = 0; j < 4; ++j) {
            int m = m0 + tx * 4 + i, o = o0 + ty * 4 + j;
            LB[(size_t)m * H + o] = accL[i][j] + fc_b[o];
            RB[(size_t)m * H + o] = accR[i][j];
        }
}

// ---------- kernel 2: per 16-pair tile: v=tanh(L_i+R_j) in LDS, 146 dots, softmax ----------
#define VSTR 772   // 768+4: float4-aligned (772*4 % 16 == 0)

__global__ __launch_bounds__(256) void pair_kernel(
    const float* __restrict__ LB, const float* __restrict__ RB,
    const float* __restrict__ Wc, const float* __restrict__ bc,
    float* __restrict__ out)
{
    __shared__ float v_s[TILE_P][VSTR];
    __shared__ int s_i[TILE_P], s_j[TILE_P];

    const int tid = threadIdx.x;
    const int b = blockIdx.y;
    const int p0 = blockIdx.x * TILE_P;

    if (tid < TILE_P) {
        int i, j;
        pair_ij(p0 + tid, i, j);
        s_i[tid] = i; s_j[tid] = j;
    }
    __syncthreads();

    // phase 1: build v = tanh(L_i + R_j)  (fc_b already folded into LB)
    const float* LBb = LB + (size_t)b * SEQ * H;
    const float* RBb = RB + (size_t)b * SEQ * H;
    for (int pp = 0; pp < TILE_P; ++pp) {
        const float* lrow = LBb + (size_t)s_i[pp] * H;
        const float* rrow = RBb + (size_t)s_j[pp] * H;
        for (int h = tid; h < H; h += 256)
            v_s[pp][h] = fast_tanh(lrow[h] + rrow[h]);
    }
    __syncthreads();

    // phase 2: 146(+pad) dots per pair; thread (tx,ty): pair tx, outputs ty+16k
    const int tx = tid & 15, ty = tid >> 4;
    const float4* vrow = reinterpret_cast<const float4*>(&v_s[tx][0]);
    const float4* wk[10];
    #pragma unroll
    for (int k = 0; k < 10; ++k)
        wk[k] = reinterpret_cast<const float4*>(Wc + (size_t)(ty + 16 * k) * H);
    float acc[10] = {0, 0, 0, 0, 0, 0, 0, 0, 0, 0};
    for (int h4 = 0; h4 < H / 4; ++h4) {
        float4 vv = vrow[h4];
        #pragma unroll
        for (int k = 0; k < 10; ++k) {
            float4 ww = wk[k][h4];
            acc[k] = fmaf(vv.x, ww.x, fmaf(vv.y, ww.y, fmaf(vv.z, ww.z, fmaf(vv.w, ww.w, acc[k]))));
        }
    }
    __syncthreads();           // v no longer needed; alias scores over it

    float* sc = &v_s[0][0];    // [TILE_P][NOUTP]
    #pragma unroll
    for (int k = 0; k < 10; ++k)
        sc[tx * NOUTP + ty + 16 * k] = acc[k];
    __syncthreads();

    // phase 3a: h2t (32 items)
    if (tid < TILE_P * 2) {
        int p = tid >> 1, t = tid & 1;
        float val = sc[p * NOUTP + t] + bc[t];
        out[(size_t)(b * NPAIR + p0 + p) * 2 + t] = val;
    }
    // phase 3b: softmax triples: 16p x 48rr
    for (int w = tid; w < TILE_P * 48; w += 256) {
        int rr = w >> 4, p = w & 15;
        int ob = 2 + rr * 3;
        float l0 = sc[p * NOUTP + ob + 0] + bc[ob + 0];
        float l1 = sc[p * NOUTP + ob + 1] + bc[ob + 1];
        float l2 = sc[p * NOUTP + ob + 2] + bc[ob + 2];
        float m = fmaxf(l0, fmaxf(l1, l2));
        float e0 = __expf(l0 - m), e1 = __expf(l1 - m), e2 = __expf(l2 - m);
        float inv = __fdividef(1.0f, e0 + e1 + e2);
        size_t base;
        if (rr < 24) base = (size_t)OFF_H2H + ((size_t)(b * 24 + rr) * NPAIR + p0 + p) * 3;
        else         base = (size_t)OFF_T2T + ((size_t)(b * 24 + (rr - 24)) * NPAIR + p0 + p) * 3;
        out[base + 0] = e0 * inv;
        out[base + 1] = e1 * inv;
        out[base + 2] = e2 * inv;
    }
}

extern "C" void kernel_launch(void* const* d_in, const int* in_sizes, int n_in,
                              void* d_out, int out_size, void* d_ws, size_t ws_size,
                              hipStream_t stream) {
    const float* hidden = (const float*)d_in[0];
    const float* fc_w   = (const float*)d_in[1];
    const float* fc_b   = (const float*)d_in[2];
    const float* h2t_w  = (const float*)d_in[3];
    const float* h2t_b  = (const float*)d_in[4];
    const float* h2h_w  = (const float*)d_in[5];
    const float* h2h_b  = (const float*)d_in[6];
    const float* t2t_w  = (const float*)d_in[7];
    const float* t2t_b  = (const float*)d_in[8];

    float* ws = (float*)d_ws;
    float* LB = ws;                         // 1024*768
    float* RB = LB + 1024 * H;              // 1024*768
    float* Wc = RB + 1024 * H;              // 160*768
    float* bc = Wc + NOUTP * H;             // 160

    float* out = (float*)d_out;

    pack_w_kernel<<<(NOUTP * H + 255) / 256, 256, 0, stream>>>(
        h2t_w, h2h_w, t2t_w, h2t_b, h2h_b, t2t_b, Wc, bc);
    lr_kernel<<<dim3(1024 / 64, H / 64), 256, 0, stream>>>(hidden, fc_w, fc_b, LB, RB);
    pair_kernel<<<dim3(NPAIR / TILE_P, 4), 256, 0, stream>>>(LB, RB, Wc, bc, out);
}

// Round 3
// 215.530 us; speedup vs baseline: 9.0391x; 9.0391x over previous
//
#include <hip/hip_runtime.h>
#include <hip/hip_bf16.h>

#define H 768
#define SEQ 256
#define NPAIR 32896
#define NOUTP 160
#define OFF_H2H 263168u            // 4*32896*2
#define OFF_T2T 9737216u           // OFF_H2H + 4*24*32896*3

#define N_BPK 122880               // 24 k32-steps * 10 frags * 64 lanes * 8 bf16
#define N_FCW 1179648              // 1536*768

typedef short bf16x8 __attribute__((ext_vector_type(8)));
typedef float f32x4 __attribute__((ext_vector_type(4)));

__device__ __forceinline__ float fast_tanh(float x) {
    // 1 - 2/(e^{2x}+1): finite for all finite x, ~1e-6 abs err
    return 1.0f - __fdividef(2.0f, __expf(2.0f * x) + 1.0f);
}
__device__ __forceinline__ float bf_lo(unsigned int w){ return __uint_as_float(w << 16); }
__device__ __forceinline__ float bf_hi(unsigned int w){ return __uint_as_float(w & 0xffff0000u); }
__device__ __forceinline__ unsigned int pack_bf16x2(float a, float b) {
    unsigned int ua = __float_as_uint(a), ub = __float_as_uint(b);
    ua += 0x7fffu + ((ua >> 16) & 1u);          // RTNE
    ub += 0x7fffu + ((ub >> 16) & 1u);
    return (ua >> 16) | (ub & 0xffff0000u);
}
__device__ __forceinline__ unsigned short bf16r(float x){
    unsigned int u = __float_as_uint(x);
    u += 0x7fffu + ((u >> 16) & 1u);
    return (unsigned short)(u >> 16);
}

// ---------------- kernel 0: pack Bpk (fragment-ordered), fcwb, bc ----------------
// Bpk linear idx = ((k32*10 + f)*64 + lane)*8 + j  ->  W[n = f*16+(lane&15)][k = k32*32+(lane>>4)*8+j]
__global__ __launch_bounds__(256) void pack_kernel(
    const float* __restrict__ h2t_w, const float* __restrict__ h2h_w,
    const float* __restrict__ t2t_w, const float* __restrict__ h2t_b,
    const float* __restrict__ h2h_b, const float* __restrict__ t2t_b,
    const float* __restrict__ fc_w,
    unsigned short* __restrict__ Bpk, unsigned short* __restrict__ fcwb,
    float* __restrict__ bc)
{
    int idx = blockIdx.x * 256 + threadIdx.x;
    if (idx < N_BPK) {
        int j = idx & 7, lane = (idx >> 3) & 63, rest = idx >> 9;
        int f = rest % 10, k32 = rest / 10;
        int n = f * 16 + (lane & 15);
        int k = k32 * 32 + ((lane >> 4) << 3) + j;
        float v = 0.f;
        if (n < 2)        v = h2t_w[n * H + k];
        else if (n < 74)  v = h2h_w[(n - 2) * H + k];
        else if (n < 146) v = t2t_w[(n - 74) * H + k];
        Bpk[idx] = bf16r(v);
    } else if (idx < N_BPK + N_FCW) {
        int q = idx - N_BPK;
        int n = q / H, k = q % H;          // n in [0,1536): 0..767 -> Wl, 768.. -> Wr
        float v = (n < H) ? fc_w[(size_t)n * 2 * H + k]
                          : fc_w[(size_t)(n - H) * 2 * H + H + k];
        fcwb[q] = bf16r(v);
    } else if (idx < N_BPK + N_FCW + NOUTP) {
        int q = idx - N_BPK - N_FCW;
        float v = 0.f;
        if (q < 2)        v = h2t_b[q];
        else if (q < 74)  v = h2h_b[q - 2];
        else if (q < 146) v = t2t_b[q - 74];
        bc[q] = v;
    }
}

// ---------------- kernel 1: LB/RB = hidden @ fc_w (bf16 MFMA GEMM, 1024x1536x768) ----------------
__global__ __launch_bounds__(256, 2) void lr_mfma(
    const float* __restrict__ hidden, const unsigned short* __restrict__ fcwb,
    const float* __restrict__ fc_b,
    unsigned short* __restrict__ LB, unsigned short* __restrict__ RB)
{
    __shared__ __align__(16) char sm[24576];          // A 8KB | B 16KB
    const int tid = threadIdx.x, l = tid & 63, w = tid >> 6;
    const int wm = w >> 1, wn = w & 1;
    const int m0 = blockIdx.x * 64, n0 = blockIdx.y * 128;
    f32x4 acc[2][4] = {};
    for (int c = 0; c < 12; ++c) {
        const int k0 = c * 64;
        #pragma unroll
        for (int it = 0; it < 2; ++it) {              // A: 64 rows x 64 k, cvt f32->bf16
            int idx = tid + it * 256;
            int row = idx >> 3, k8 = idx & 7;
            const float4* src = reinterpret_cast<const float4*>(hidden + (size_t)(m0 + row) * H + k0 + k8 * 8);
            float4 a = src[0], bq = src[1];
            int4 st;
            st.x = pack_bf16x2(a.x, a.y);  st.y = pack_bf16x2(a.z, a.w);
            st.z = pack_bf16x2(bq.x, bq.y); st.w = pack_bf16x2(bq.z, bq.w);
            *reinterpret_cast<int4*>(sm + row * 128 + ((k8 * 16) ^ ((row & 7) << 4))) = st;
        }
        #pragma unroll
        for (int it = 0; it < 4; ++it) {              // B: 128 rows x 64 k
            int idx = tid + it * 256;
            int row = idx >> 3, k8 = idx & 7;
            *reinterpret_cast<int4*>(sm + 8192 + row * 128 + ((k8 * 16) ^ ((row & 7) << 4))) =
                *reinterpret_cast<const int4*>(fcwb + (size_t)(n0 + row) * H + k0 + k8 * 8);
        }
        __syncthreads();
        #pragma unroll
        for (int kk = 0; kk < 2; ++kk) {
            const int sl = kk * 4 + (l >> 4);
            const int swz = (l & 7) << 4;
            bf16x8 af[2], bfr[4];
            #pragma unroll
            for (int a = 0; a < 2; ++a) {
                int row = 32 * wm + 16 * a + (l & 15);
                af[a] = *reinterpret_cast<const bf16x8*>(sm + row * 128 + ((sl * 16) ^ swz));
            }
            #pragma unroll
            for (int f = 0; f < 4; ++f) {
                int row = 64 * wn + 16 * f + (l & 15);
                bfr[f] = *reinterpret_cast<const bf16x8*>(sm + 8192 + row * 128 + ((sl * 16) ^ swz));
            }
            #pragma unroll
            for (int a = 0; a < 2; ++a)
                #pragma unroll
                for (int f = 0; f < 4; ++f)
                    acc[a][f] = __builtin_amdgcn_mfma_f32_16x16x32_bf16(af[a], bfr[f], acc[a][f], 0, 0, 0);
        }
        __syncthreads();
    }
    #pragma unroll
    for (int a = 0; a < 2; ++a)
        #pragma unroll
        for (int f = 0; f < 4; ++f)
            #pragma unroll
            for (int r = 0; r < 4; ++r) {
                int row = m0 + 32 * wm + 16 * a + 4 * (l >> 4) + r;
                int col = n0 + 64 * wn + 16 * f + (l & 15);
                float v = acc[a][f][r];
                if (n0 < H) LB[(size_t)row * H + col] = bf16r(v + fc_b[col]);  // fold fc_b into L
                else        RB[(size_t)row * H + (col - H)] = bf16r(v);
            }
}

// ---------------- kernel 2: triangle-tiled MFMA pair kernel ----------------
// tile = 16 i-rows x 16 j-cols = 256 pairs (M), N = 160 (padded 146), K = 768, KC = 64
__global__ __launch_bounds__(256, 2) void pair_mfma(
    const unsigned short* __restrict__ LB, const unsigned short* __restrict__ RB,
    const unsigned short* __restrict__ Bpk, const float* __restrict__ bc,
    float* __restrict__ out)
{
    __shared__ __align__(16) char sm[53248];          // A 32KB | B 20KB ; epilogue: 4x 11008B score slabs
    __shared__ float bc_s[160];
    const int tid = threadIdx.x, l = tid & 63, w = tid >> 6;
    const int b = blockIdx.y;
    if (tid < 160) bc_s[tid] = bc[tid];

    int t = blockIdx.x;                                // upper-tri tile decode (16x16 tile grid)
    int TI = 0;
    while (TI < 15 && (16 * (TI + 1) - ((TI + 1) * TI) / 2) <= t) ++TI;
    const int TJ = TI + (t - (16 * TI - (TI * (TI - 1)) / 2));
    const int i0 = TI * 16, j0 = TJ * 16;

    const unsigned short* LBb = LB + (size_t)b * SEQ * H;
    const unsigned short* RBb = RB + (size_t)b * SEQ * H;

    f32x4 acc[4][10] = {};
    for (int c = 0; c < 12; ++c) {
        const int k0 = c * 64;
        #pragma unroll
        for (int it = 0; it < 8; ++it) {               // A: v = tanh(L_i + R_j), 256 rows x 64 k
            int idx = tid + it * 256;
            int q = idx >> 3, k8 = idx & 7;            // q = ii*16 + jj
            int i = i0 + (q >> 4), j = j0 + (q & 15);
            int4 lv = *reinterpret_cast<const int4*>(LBb + (size_t)i * H + k0 + k8 * 8);
            int4 rv = *reinterpret_cast<const int4*>(RBb + (size_t)j * H + k0 + k8 * 8);
            float t0 = fast_tanh(bf_lo(lv.x) + bf_lo(rv.x));
            float t1 = fast_tanh(bf_hi(lv.x) + bf_hi(rv.x));
            float t2 = fast_tanh(bf_lo(lv.y) + bf_lo(rv.y));
            float t3 = fast_tanh(bf_hi(lv.y) + bf_hi(rv.y));
            float t4 = fast_tanh(bf_lo(lv.z) + bf_lo(rv.z));
            float t5 = fast_tanh(bf_hi(lv.z) + bf_hi(rv.z));
            float t6 = fast_tanh(bf_lo(lv.w) + bf_lo(rv.w));
            float t7 = fast_tanh(bf_hi(lv.w) + bf_hi(rv.w));
            int4 st;
            st.x = pack_bf16x2(t0, t1); st.y = pack_bf16x2(t2, t3);
            st.z = pack_bf16x2(t4, t5); st.w = pack_bf16x2(t6, t7);
            *reinterpret_cast<int4*>(sm + q * 128 + ((k8 * 16) ^ ((q & 7) << 4))) = st;
        }
        {                                              // B: fragment-ordered linear copy, 20KB
            const unsigned short* bsrc = Bpk + (size_t)c * 10240;
            #pragma unroll
            for (int it = 0; it < 5; ++it) {
                int off = (tid + it * 256) * 8;        // bf16 units
                *reinterpret_cast<int4*>(sm + 32768 + off * 2) =
                    *reinterpret_cast<const int4*>(bsrc + off);
            }
        }
        __syncthreads();
        #pragma unroll
        for (int kk = 0; kk < 2; ++kk) {
            const int sl = kk * 4 + (l >> 4);
            const int swz = (l & 7) << 4;
            bf16x8 af[4];
            #pragma unroll
            for (int m = 0; m < 4; ++m) {
                int row = 64 * w + 16 * m + (l & 15);
                af[m] = *reinterpret_cast<const bf16x8*>(sm + row * 128 + ((sl * 16) ^ swz));
            }
            #pragma unroll
            for (int f = 0; f < 10; ++f) {
                bf16x8 bfr = *reinterpret_cast<const bf16x8*>(sm + 32768 + ((kk * 10 + f) * 64 + l) * 16);
                #pragma unroll
                for (int m = 0; m < 4; ++m)
                    acc[m][f] = __builtin_amdgcn_mfma_f32_16x16x32_bf16(af[m], bfr, acc[m][f], 0, 0, 0);
            }
        }
        __syncthreads();
    }

    // epilogue: per M-frag (one i-row each): scores -> wave-private LDS -> bias/softmax -> out
    float* scw = reinterpret_cast<float*>(sm + w * 11008);   // [16][172] f32
    #pragma unroll
    for (int m = 0; m < 4; ++m) {
        asm volatile("s_waitcnt lgkmcnt(0)" ::: "memory");   // prev frag's reads retired
        #pragma unroll
        for (int f = 0; f < 10; ++f)
            #pragma unroll
            for (int r = 0; r < 4; ++r)
                scw[(4 * (l >> 4) + r) * 172 + f * 16 + (l & 15)] = acc[m][f][r];
        asm volatile("s_waitcnt lgkmcnt(0)" ::: "memory");   // writes visible wave-wide
        const int i = i0 + 4 * w + m;
        const int pbase = i * SEQ - (i * (i - 1)) / 2 - i + j0;   // p = pbase + jj
        if (l < 32) {                                        // h2t
            int jj = l >> 1, tt = l & 1;
            if (j0 + jj >= i)
                out[((size_t)b * NPAIR + pbase + jj) * 2 + tt] = scw[jj * 172 + tt] + bc_s[tt];
        }
        for (int it = 0; it < 12; ++it) {                    // 16 jj x 48 triples
            int item = it * 64 + l;
            int jj = item & 15, rr = item >> 4;
            if (j0 + jj >= i) {
                int ob = 2 + rr * 3;
                float l0 = scw[jj * 172 + ob + 0] + bc_s[ob + 0];
                float l1 = scw[jj * 172 + ob + 1] + bc_s[ob + 1];
                float l2 = scw[jj * 172 + ob + 2] + bc_s[ob + 2];
                float mx = fmaxf(l0, fmaxf(l1, l2));
                float e0 = __expf(l0 - mx), e1 = __expf(l1 - mx), e2 = __expf(l2 - mx);
                float inv = __fdividef(1.0f, e0 + e1 + e2);
                int p = pbase + jj;
                size_t base;
                if (rr < 24) base = (size_t)OFF_H2H + ((size_t)(b * 24 + rr) * NPAIR + p) * 3;
                else         base = (size_t)OFF_T2T + ((size_t)(b * 24 + rr - 24) * NPAIR + p) * 3;
                out[base + 0] = e0 * inv;
                out[base + 1] = e1 * inv;
                out[base + 2] = e2 * inv;
            }
        }
    }
}

extern "C" void kernel_launch(void* const* d_in, const int* in_sizes, int n_in,
                              void* d_out, int out_size, void* d_ws, size_t ws_size,
                              hipStream_t stream) {
    const float* hidden = (const float*)d_in[0];
    const float* fc_w   = (const float*)d_in[1];
    const float* fc_b   = (const float*)d_in[2];
    const float* h2t_w  = (const float*)d_in[3];
    const float* h2t_b  = (const float*)d_in[4];
    const float* h2h_w  = (const float*)d_in[5];
    const float* h2h_b  = (const float*)d_in[6];
    const float* t2t_w  = (const float*)d_in[7];
    const float* t2t_b  = (const float*)d_in[8];

    char* wsb = (char*)d_ws;
    unsigned short* LBw  = (unsigned short*)(wsb);              // 1024*768 bf16 = 1.5 MB
    unsigned short* RBw  = (unsigned short*)(wsb + 1572864);    // 1.5 MB
    unsigned short* Bpk  = (unsigned short*)(wsb + 3145728);    // 240 KB
    unsigned short* fcwb = (unsigned short*)(wsb + 3391488);    // 2.25 MB
    float*          bc   = (float*)        (wsb + 5750784);     // 640 B

    float* out = (float*)d_out;

    pack_kernel<<<(N_BPK + N_FCW + NOUTP + 255) / 256, 256, 0, stream>>>(
        h2t_w, h2h_w, t2t_w, h2t_b, h2h_b, t2t_b, fc_w, Bpk, fcwb, bc);
    lr_mfma<<<dim3(16, 12), 256, 0, stream>>>(hidden, fcwb, fc_b, LBw, RBw);
    pair_mfma<<<dim3(136, 4), 256, 0, stream>>>(LBw, RBw, Bpk, bc, out);
}

// Round 4
// 97.523 us; speedup vs baseline: 19.9769x; 2.2101x over previous
//
#include <hip/hip_runtime.h>
#include <hip/hip_bf16.h>

#define H 768
#define SEQ 256
#define NPAIR 32896                // S*(S+1)/2 = 257*128
#define NOUTP 160
#define OFF_H2H 263168u            // 4*32896*2
#define OFF_T2T 9737216u           // OFF_H2H + 4*24*32896*3

#define N_BPK 122880               // 24 k32-steps * 10 frags * 64 lanes * 8 bf16
#define N_FCW 1179648              // 1536*768

typedef short bf16x8 __attribute__((ext_vector_type(8)));
typedef float f32x4 __attribute__((ext_vector_type(4)));

__device__ __forceinline__ float tanh_act(float x) {
    // tanh(x) = 1 - 2/(e^{2x}+1); e^{2x} = exp2(x * 2*log2(e)). 3 VALU + 2 trans.
    float e = __builtin_amdgcn_exp2f(x * 2.8853900817779268f);
    return fmaf(-2.0f, __builtin_amdgcn_rcpf(e + 1.0f), 1.0f);
}
__device__ __forceinline__ float bf_lo(int w){ return __uint_as_float(((unsigned)w) << 16); }
__device__ __forceinline__ float bf_hi(int w){ return __uint_as_float(((unsigned)w) & 0xffff0000u); }
__device__ __forceinline__ int cvtpk(float lo, float hi) {
    int r;
    asm("v_cvt_pk_bf16_f32 %0, %1, %2" : "=v"(r) : "v"(lo), "v"(hi));
    return r;
}
__device__ __forceinline__ unsigned short bf16r(float x){
    unsigned int u = __float_as_uint(x);
    u += 0x7fffu + ((u >> 16) & 1u);
    return (unsigned short)(u >> 16);
}

__device__ __forceinline__ int row_start(int i) { return i * SEQ - (i * (i - 1)) / 2; }
__device__ __forceinline__ void pair_ij(int p, int& oi, int& oj) {
    double disc = 263169.0 - 8.0 * (double)p;   // (2S+1)^2 - 8p
    int i = (int)((513.0 - sqrt(disc)) * 0.5);
    if (i > 0 && row_start(i) > p) --i;
    while (row_start(i + 1) <= p) ++i;
    oi = i;
    oj = i + (p - row_start(i));
}

// ---------------- kernel 0: pack Bpk (fragment-ordered), fcwb, bc ----------------
// Bpk linear idx = ((k32*10 + f)*64 + lane)*8 + j -> W[n=f*16+(lane&15)][k=k32*32+(lane>>4)*8+j]
__global__ __launch_bounds__(256) void pack_kernel(
    const float* __restrict__ h2t_w, const float* __restrict__ h2h_w,
    const float* __restrict__ t2t_w, const float* __restrict__ h2t_b,
    const float* __restrict__ h2h_b, const float* __restrict__ t2t_b,
    const float* __restrict__ fc_w,
    unsigned short* __restrict__ Bpk, unsigned short* __restrict__ fcwb,
    float* __restrict__ bc)
{
    int idx = blockIdx.x * 256 + threadIdx.x;
    if (idx < N_BPK) {
        int j = idx & 7, lane = (idx >> 3) & 63, rest = idx >> 9;
        int f = rest % 10, k32 = rest / 10;
        int n = f * 16 + (lane & 15);
        int k = k32 * 32 + ((lane >> 4) << 3) + j;
        float v = 0.f;
        if (n < 2)        v = h2t_w[n * H + k];
        else if (n < 74)  v = h2h_w[(n - 2) * H + k];
        else if (n < 146) v = t2t_w[(n - 74) * H + k];
        Bpk[idx] = bf16r(v);
    } else if (idx < N_BPK + N_FCW) {
        int q = idx - N_BPK;
        int n = q / H, k = q % H;          // n in [0,1536): 0..767 -> Wl, 768.. -> Wr
        float v = (n < H) ? fc_w[(size_t)n * 2 * H + k]
                          : fc_w[(size_t)(n - H) * 2 * H + H + k];
        fcwb[q] = bf16r(v);
    } else if (idx < N_BPK + N_FCW + NOUTP) {
        int q = idx - N_BPK - N_FCW;
        float v = 0.f;
        if (q < 2)        v = h2t_b[q];
        else if (q < 74)  v = h2h_b[q - 2];
        else if (q < 146) v = t2t_b[q - 74];
        bc[q] = v;
    }
}

// ---------------- kernel 1: LB/RB = hidden @ fc_w (bf16 MFMA GEMM, 1024x1536x768) ----------------
__global__ __launch_bounds__(256, 2) void lr_mfma(
    const float* __restrict__ hidden, const unsigned short* __restrict__ fcwb,
    const float* __restrict__ fc_b,
    unsigned short* __restrict__ LB, unsigned short* __restrict__ RB)
{
    __shared__ __align__(16) char sm[24576];          // A 8KB | B 16KB
    const int tid = threadIdx.x, l = tid & 63, w = tid >> 6;
    const int wm = w >> 1, wn = w & 1;
    const int m0 = blockIdx.x * 64, n0 = blockIdx.y * 128;
    f32x4 acc[2][4] = {};
    for (int c = 0; c < 12; ++c) {
        const int k0 = c * 64;
        #pragma unroll
        for (int it = 0; it < 2; ++it) {              // A: 64 rows x 64 k, cvt f32->bf16
            int idx = tid + it * 256;
            int row = idx >> 3, k8 = idx & 7;
            const float4* src = reinterpret_cast<const float4*>(hidden + (size_t)(m0 + row) * H + k0 + k8 * 8);
            float4 a = src[0], bq = src[1];
            int4 st;
            st.x = cvtpk(a.x, a.y);  st.y = cvtpk(a.z, a.w);
            st.z = cvtpk(bq.x, bq.y); st.w = cvtpk(bq.z, bq.w);
            *reinterpret_cast<int4*>(sm + row * 128 + ((k8 * 16) ^ ((row & 7) << 4))) = st;
        }
        #pragma unroll
        for (int it = 0; it < 4; ++it) {              // B: 128 rows x 64 k
            int idx = tid + it * 256;
            int row = idx >> 3, k8 = idx & 7;
            *reinterpret_cast<int4*>(sm + 8192 + row * 128 + ((k8 * 16) ^ ((row & 7) << 4))) =
                *reinterpret_cast<const int4*>(fcwb + (size_t)(n0 + row) * H + k0 + k8 * 8);
        }
        __syncthreads();
        #pragma unroll
        for (int kk = 0; kk < 2; ++kk) {
            const int sl = kk * 4 + (l >> 4);
            const int swz = (l & 7) << 4;
            bf16x8 af[2], bfr[4];
            #pragma unroll
            for (int a = 0; a < 2; ++a) {
                int row = 32 * wm + 16 * a + (l & 15);
                af[a] = *reinterpret_cast<const bf16x8*>(sm + row * 128 + ((sl * 16) ^ swz));
            }
            #pragma unroll
            for (int f = 0; f < 4; ++f) {
                int row = 64 * wn + 16 * f + (l & 15);
                bfr[f] = *reinterpret_cast<const bf16x8*>(sm + 8192 + row * 128 + ((sl * 16) ^ swz));
            }
            #pragma unroll
            for (int a = 0; a < 2; ++a)
                #pragma unroll
                for (int f = 0; f < 4; ++f)
                    acc[a][f] = __builtin_amdgcn_mfma_f32_16x16x32_bf16(af[a], bfr[f], acc[a][f], 0, 0, 0);
        }
        __syncthreads();
    }
    #pragma unroll
    for (int a = 0; a < 2; ++a)
        #pragma unroll
        for (int f = 0; f < 4; ++f)
            #pragma unroll
            for (int r = 0; r < 4; ++r) {
                int row = m0 + 32 * wm + 16 * a + 4 * (l >> 4) + r;
                int col = n0 + 64 * wn + 16 * f + (l & 15);
                float v = acc[a][f][r];
                if (n0 < H) LB[(size_t)row * H + col] = bf16r(v + fc_b[col]);  // fold fc_b into L
                else        RB[(size_t)row * H + (col - H)] = bf16r(v);
            }
}

// ---------------- kernel 2: linear-pair MFMA kernel ----------------
// block = 512 thr (8 waves = 4 wm x 2 wn), M-tile = 128 pairs, N = 160, KC = 64
// wave tile = 32M x 80N  (2 x 5 frags, 40 acc VGPRs)
__device__ __forceinline__ void stage_row(char* dst, const unsigned short* lp, const unsigned short* rp) {
    int4 lv = *reinterpret_cast<const int4*>(lp);
    int4 rv = *reinterpret_cast<const int4*>(rp);
    int4 st;
    st.x = cvtpk(tanh_act(bf_lo(lv.x) + bf_lo(rv.x)), tanh_act(bf_hi(lv.x) + bf_hi(rv.x)));
    st.y = cvtpk(tanh_act(bf_lo(lv.y) + bf_lo(rv.y)), tanh_act(bf_hi(lv.y) + bf_hi(rv.y)));
    st.z = cvtpk(tanh_act(bf_lo(lv.z) + bf_lo(rv.z)), tanh_act(bf_hi(lv.z) + bf_hi(rv.z)));
    st.w = cvtpk(tanh_act(bf_lo(lv.w) + bf_lo(rv.w)), tanh_act(bf_hi(lv.w) + bf_hi(rv.w)));
    *reinterpret_cast<int4*>(dst) = st;
}

__global__ __launch_bounds__(512, 4) void pair_mfma(
    const unsigned short* __restrict__ LB, const unsigned short* __restrict__ RB,
    const unsigned short* __restrict__ Bpk, const float* __restrict__ bc,
    float* __restrict__ out)
{
    __shared__ __align__(16) char sm[38528];
    // A [0,16384) | B [16384,36864) | iOf [36864,37376) | jOf [37376,37888) | bc_s [37888,38528)
    // epilogue: scores [32][172] f32 alias at [0,22528)
    int*   iOf  = reinterpret_cast<int*>(sm + 36864);
    int*   jOf  = reinterpret_cast<int*>(sm + 37376);
    float* bc_s = reinterpret_cast<float*>(sm + 37888);

    const int tid = threadIdx.x, l = tid & 63, w = tid >> 6;
    const int wm = w >> 1, wn = w & 1;
    const int b = blockIdx.y, p0 = blockIdx.x * 128;

    if (tid < 128) {
        int i, j; pair_ij(p0 + tid, i, j);
        iOf[tid] = i * H; jOf[tid] = j * H;
    }
    if (tid < NOUTP) bc_s[tid] = bc[tid];
    __syncthreads();

    const unsigned short* LBb = LB + (size_t)b * SEQ * H;
    const unsigned short* RBb = RB + (size_t)b * SEQ * H;
    const int qA = tid >> 3, k8 = tid & 7;
    const unsigned short* lpA = LBb + iOf[qA] + k8 * 8;       // rows qA and qA+64, const per thread
    const unsigned short* rpA = RBb + jOf[qA] + k8 * 8;
    const unsigned short* lpB = LBb + iOf[qA + 64] + k8 * 8;
    const unsigned short* rpB = RBb + jOf[qA + 64] + k8 * 8;
    char* stA = sm + qA * 128 + ((k8 * 16) ^ ((qA & 7) << 4));
    char* stB = stA + 64 * 128;                               // (qA+64)&7 == qA&7

    f32x4 acc[2][5] = {};
    const int4* bsrc = reinterpret_cast<const int4*>(Bpk);
    int4* bdst = reinterpret_cast<int4*>(sm + 16384);

    for (int c = 0; c < 12; ++c) {
        const int k0 = c * 64;
        stage_row(stA, lpA + k0, rpA + k0);                   // A: v = tanh(L+R) -> bf16, swizzled
        stage_row(stB, lpB + k0, rpB + k0);
        bdst[tid]        = bsrc[c * 1280 + tid];              // B: fragment-ordered linear copy 20KB
        bdst[tid + 512]  = bsrc[c * 1280 + tid + 512];
        if (tid < 256) bdst[tid + 1024] = bsrc[c * 1280 + tid + 1024];
        __syncthreads();
        #pragma unroll
        for (int kk = 0; kk < 2; ++kk) {
            const int sl16 = (kk * 4 + (l >> 4)) * 16;
            const int swz = (l & 7) << 4;
            bf16x8 af[2];
            #pragma unroll
            for (int m = 0; m < 2; ++m) {
                int row = 32 * wm + 16 * m + (l & 15);
                af[m] = *reinterpret_cast<const bf16x8*>(sm + row * 128 + (sl16 ^ swz));
            }
            #pragma unroll
            for (int f = 0; f < 5; ++f) {
                bf16x8 bfr = *reinterpret_cast<const bf16x8*>(
                    sm + 16384 + ((kk * 10 + wn * 5 + f) * 64 + l) * 16);
                #pragma unroll
                for (int m = 0; m < 2; ++m)
                    acc[m][f] = __builtin_amdgcn_mfma_f32_16x16x32_bf16(af[m], bfr, acc[m][f], 0, 0, 0);
            }
        }
        __syncthreads();
    }

    // epilogue: 4 steps of 32 rows; wave-group wm==s writes its scores, all waves do softmax
    float* scw = reinterpret_cast<float*>(sm);               // [32][172]
    for (int s = 0; s < 4; ++s) {
        if (wm == s) {
            #pragma unroll
            for (int m = 0; m < 2; ++m)
                #pragma unroll
                for (int f = 0; f < 5; ++f)
                    #pragma unroll
                    for (int r = 0; r < 4; ++r) {
                        int rl = 16 * m + 4 * (l >> 4) + r;
                        int col = 80 * wn + 16 * f + (l & 15);
                        scw[rl * 172 + col] = acc[m][f][r];
                    }
        }
        __syncthreads();
        if (tid < 64) {                                      // h2t: 32 rows x 2
            int rl = tid >> 1, tt = tid & 1;
            int p = p0 + 32 * s + rl;
            out[((size_t)b * NPAIR + p) * 2 + tt] = scw[rl * 172 + tt] + bc_s[tt];
        }
        #pragma unroll
        for (int it = 0; it < 3; ++it) {                     // 32 rows x 48 triples
            int item = it * 512 + tid;
            int rl = item & 31, rr = item >> 5;
            int ob = 2 + rr * 3;
            float l0 = scw[rl * 172 + ob + 0] + bc_s[ob + 0];
            float l1 = scw[rl * 172 + ob + 1] + bc_s[ob + 1];
            float l2 = scw[rl * 172 + ob + 2] + bc_s[ob + 2];
            float mx = fmaxf(l0, fmaxf(l1, l2));
            float e0 = __expf(l0 - mx), e1 = __expf(l1 - mx), e2 = __expf(l2 - mx);
            float inv = __fdividef(1.0f, e0 + e1 + e2);
            int p = p0 + 32 * s + rl;
            size_t base = (rr < 24)
                ? (size_t)OFF_H2H + ((size_t)(b * 24 + rr) * NPAIR + p) * 3
                : (size_t)OFF_T2T + ((size_t)(b * 24 + rr - 24) * NPAIR + p) * 3;
            out[base + 0] = e0 * inv;
            out[base + 1] = e1 * inv;
            out[base + 2] = e2 * inv;
        }
        __syncthreads();
    }
}

extern "C" void kernel_launch(void* const* d_in, const int* in_sizes, int n_in,
                              void* d_out, int out_size, void* d_ws, size_t ws_size,
                              hipStream_t stream) {
    const float* hidden = (const float*)d_in[0];
    const float* fc_w   = (const float*)d_in[1];
    const float* fc_b   = (const float*)d_in[2];
    const float* h2t_w  = (const float*)d_in[3];
    const float* h2t_b  = (const float*)d_in[4];
    const float* h2h_w  = (const float*)d_in[5];
    const float* h2h_b  = (const float*)d_in[6];
    const float* t2t_w  = (const float*)d_in[7];
    const float* t2t_b  = (const float*)d_in[8];

    char* wsb = (char*)d_ws;
    unsigned short* LBw  = (unsigned short*)(wsb);              // 1024*768 bf16 = 1.5 MB
    unsigned short* RBw  = (unsigned short*)(wsb + 1572864);    // 1.5 MB
    unsigned short* Bpk  = (unsigned short*)(wsb + 3145728);    // 240 KB
    unsigned short* fcwb = (unsigned short*)(wsb + 3391488);    // 2.25 MB
    float*          bc   = (float*)        (wsb + 5750784);     // 640 B

    float* out = (float*)d_out;

    pack_kernel<<<(N_BPK + N_FCW + NOUTP + 255) / 256, 256, 0, stream>>>(
        h2t_w, h2h_w, t2t_w, h2t_b, h2h_b, t2t_b, fc_w, Bpk, fcwb, bc);
    lr_mfma<<<dim3(16, 12), 256, 0, stream>>>(hidden, fcwb, fc_b, LBw, RBw);
    pair_mfma<<<dim3(NPAIR / 128, 4), 512, 0, stream>>>(LBw, RBw, Bpk, bc, out);
}